// Round 1
// baseline (166.582 us; speedup 1.0000x reference)
//
#include <hip/hip_runtime.h>
#include <hip/hip_bf16.h>

// Problem constants (from reference)
#define BB 4
#define WW 32
#define HH 32
#define CC 128
#define SS 256
#define DD 512
#define NC 64
// pixels = B*W*H = 4096

// ---------------------------------------------------------------------------
// Kernel A: text projections. te = s * a;  ks = te@Wks + bks; vs = te@Wvs+bvs
// grid = (B*S)/4 = 256 blocks, 128 threads. 4 text rows per block (LDS).
// Wave0 (t<64) computes ks columns, wave1 computes vs columns -> coalesced W.
// ---------------------------------------------------------------------------
__global__ __launch_bounds__(128) void text_proj_kernel(
    const float* __restrict__ s, const float* __restrict__ a,
    const float* __restrict__ Wks, const float* __restrict__ bks,
    const float* __restrict__ Wvs, const float* __restrict__ bvs,
    float* __restrict__ ksw, float* __restrict__ vsw)
{
    __shared__ float tel[4][DD];
    const int t = threadIdx.x;
    const int row0 = blockIdx.x * 4;   // global row in [0, B*S)

    for (int r = 0; r < 4; ++r) {
        const float am = a[row0 + r];
        const float* srow = s + (size_t)(row0 + r) * DD;
        for (int i = t; i < DD; i += 128) tel[r][i] = srow[i] * am;
    }
    __syncthreads();

    const int col = t & 63;
    const float* Wm = (t < 64) ? Wks : Wvs;
    float bias = (t < 64) ? bks[col] : bvs[col];
    float acc0 = bias, acc1 = bias, acc2 = bias, acc3 = bias;
    for (int i = 0; i < DD; ++i) {
        const float w = Wm[i * NC + col];
        acc0 += tel[0][i] * w;
        acc1 += tel[1][i] * w;
        acc2 += tel[2][i] * w;
        acc3 += tel[3][i] * w;
    }
    float* dst = (t < 64) ? ksw : vsw;
    dst[(row0 + 0) * NC + col] = acc0;
    dst[(row0 + 1) * NC + col] = acc1;
    dst[(row0 + 2) * NC + col] = acc2;
    dst[(row0 + 3) * NC + col] = acc3;
}

// ---------------------------------------------------------------------------
// Kernel B: per-batch reductions over s.
//   M[b,c,d] = sum_s vs[b,s,c]*ks[b,s,d]
//   Ks[b,d]  = sum_s ks[b,s,d]
//   Vs[b,c]  = sum_s vs[b,s,c]
// grid = B*64 blocks (one per (b,c)), 64 threads (one per d).
// ---------------------------------------------------------------------------
__global__ __launch_bounds__(64) void reduce_kernel(
    const float* __restrict__ ksw, const float* __restrict__ vsw,
    float* __restrict__ Mw, float* __restrict__ Ksw, float* __restrict__ Vsw)
{
    const int b = blockIdx.x >> 6;
    const int c = blockIdx.x & 63;
    const int d = threadIdx.x;

    float acc = 0.f, ksum = 0.f, vsum = 0.f;
    const float* vsb = vsw + (size_t)b * SS * NC;
    const float* ksb = ksw + (size_t)b * SS * NC;
    for (int s2 = 0; s2 < SS; ++s2) {
        const float vv = vsb[s2 * NC + c];   // broadcast (same addr all lanes)
        const float kv = ksb[s2 * NC + d];   // coalesced
        acc  += vv * kv;
        ksum += kv;
        vsum += vv;
    }
    Mw[((size_t)b * NC + c) * NC + d] = acc;
    if (c == 0) Ksw[b * NC + d] = ksum;
    if (d == 0) Vsw[b * NC + c] = vsum;
}

// ---------------------------------------------------------------------------
// Kernel C: per-pixel fused attention + output proj + residual + layernorm.
// grid = B*W*H = 4096 blocks, 128 threads.
//   attn_pre[c,d] = ( vx[c]*(S*kx[d]+Ks[d]) + Vs[c]*kx[d] + M[c,d] ) / 8
//   P = softmax_rows(attn_pre);  out[d] = sum_c q[c]*P[c,d]
//   y = out@Wout + bout + x;  layernorm(y)
// LDS 2D tiles padded to 65 to keep bank access conflict-free.
// ---------------------------------------------------------------------------
__global__ __launch_bounds__(128) void pixel_kernel(
    const float* __restrict__ x,
    const float* __restrict__ Wq,  const float* __restrict__ bq,
    const float* __restrict__ Wkx, const float* __restrict__ bkx,
    const float* __restrict__ Wvx, const float* __restrict__ bvx,
    const float* __restrict__ Wout, const float* __restrict__ bout,
    const float* __restrict__ ln_scale, const float* __restrict__ ln_bias,
    const float* __restrict__ Mw, const float* __restrict__ Ksw,
    const float* __restrict__ Vsw,
    float* __restrict__ out)
{
    __shared__ float xl[CC];
    __shared__ float kxl[NC], vxl[NC], ql[NC], kkl[NC], rsl[NC], outl[NC];
    __shared__ float Ml[NC * 65];
    __shared__ float Pl[NC * 65];
    __shared__ float red[4];

    const int t = threadIdx.x;
    const int p = blockIdx.x;      // pixel index 0..4095
    const int b = p >> 10;         // W*H = 1024 pixels per batch

    // stage x row and per-batch M tile
    xl[t] = x[(size_t)p * CC + t];
    {
        const float* Mb = Mw + (size_t)b * NC * NC;
        for (int idx = t; idx < NC * NC; idx += 128) {
            const int c = idx >> 6, d = idx & 63;
            Ml[c * 65 + d] = Mb[idx];
        }
    }
    __syncthreads();

    // phase 1: projections q/kx/vx (dots of length 128)
    {
        const int col = t & 63;
        const float* Wm = (t < 64) ? Wkx : Wvx;
        float acc = (t < 64) ? bkx[col] : bvx[col];
        for (int i = 0; i < CC; ++i) acc += xl[i] * Wm[i * NC + col];
        if (t < 64) kxl[col] = acc; else vxl[col] = acc;
        if (t < 64) {
            float aq = bq[t];
            for (int i = 0; i < CC; ++i) aq += xl[i] * Wq[i * NC + t];
            ql[t] = aq;
        }
    }
    __syncthreads();
    if (t < 64) kkl[t] = 256.0f * kxl[t] + Ksw[b * NC + t];
    __syncthreads();

    // phase 2: one attn row per thread (wave0), softmax, fold q/sum scale
    if (t < 64) {
        const int c = t;
        const float vxc = vxl[c];
        const float vsc = Vsw[b * NC + c];
        float row[NC];
        float mx = -3.4e38f;
        #pragma unroll
        for (int d = 0; d < NC; ++d) {
            const float v = (vxc * kkl[d] + vsc * kxl[d] + Ml[c * 65 + d]) * 0.125f;
            row[d] = v;
            mx = fmaxf(mx, v);
        }
        float sum = 0.f;
        #pragma unroll
        for (int d = 0; d < NC; ++d) {
            const float e = __expf(row[d] - mx);
            sum += e;
            Pl[c * 65 + d] = e;
        }
        rsl[c] = ql[c] / sum;
    }
    __syncthreads();

    // phase 3: out[d] = sum_j rs[j] * P[j,d]   (column sums, conflict-free)
    if (t < 64) {
        float acc = 0.f;
        #pragma unroll
        for (int j = 0; j < NC; ++j) acc += rsl[j] * Pl[j * 65 + t];
        outl[t] = acc;
    }
    __syncthreads();

    // phase 4: output projection + residual
    float y;
    {
        float acc = bout[t];
        for (int k2 = 0; k2 < NC; ++k2) acc += outl[k2] * Wout[k2 * CC + t];
        y = acc + xl[t];
    }

    // phase 5: layernorm over 128 channels (2 waves)
    float s1 = y, s2 = y * y;
    for (int off = 32; off >= 1; off >>= 1) {
        s1 += __shfl_down(s1, off);
        s2 += __shfl_down(s2, off);
    }
    if ((t & 63) == 0) { red[(t >> 6) * 2] = s1; red[(t >> 6) * 2 + 1] = s2; }
    __syncthreads();
    const float S1 = red[0] + red[2];
    const float S2 = red[1] + red[3];
    const float mu = S1 * (1.0f / 128.0f);
    const float var = S2 * (1.0f / 128.0f) - mu * mu;
    const float rstd = rsqrtf(var + 1e-6f);
    out[(size_t)p * CC + t] = (y - mu) * rstd * ln_scale[t] + ln_bias[t];
}

// ---------------------------------------------------------------------------
extern "C" void kernel_launch(void* const* d_in, const int* in_sizes, int n_in,
                              void* d_out, int out_size, void* d_ws, size_t ws_size,
                              hipStream_t stream) {
    const float* x        = (const float*)d_in[0];
    const float* s        = (const float*)d_in[1];
    const float* a        = (const float*)d_in[2];
    const float* Wq       = (const float*)d_in[3];
    const float* bq       = (const float*)d_in[4];
    const float* Wkx      = (const float*)d_in[5];
    const float* bkx      = (const float*)d_in[6];
    const float* Wvx      = (const float*)d_in[7];
    const float* bvx      = (const float*)d_in[8];
    const float* Wks      = (const float*)d_in[9];
    const float* bks      = (const float*)d_in[10];
    const float* Wvs      = (const float*)d_in[11];
    const float* bvs      = (const float*)d_in[12];
    const float* Wout     = (const float*)d_in[13];
    const float* bout     = (const float*)d_in[14];
    const float* ln_scale = (const float*)d_in[15];
    const float* ln_bias  = (const float*)d_in[16];

    float* ws  = (float*)d_ws;
    float* ksw = ws;                 // B*S*64 = 65536
    float* vsw = ws + 65536;         // 65536
    float* Mw  = ws + 131072;        // B*64*64 = 16384
    float* Ksw = ws + 147456;        // B*64 = 256
    float* Vsw = ws + 147712;        // B*64 = 256

    text_proj_kernel<<<(BB * SS) / 4, 128, 0, stream>>>(s, a, Wks, bks, Wvs, bvs, ksw, vsw);
    reduce_kernel<<<BB * NC, 64, 0, stream>>>(ksw, vsw, Mw, Ksw, Vsw);
    pixel_kernel<<<BB * WW * HH, 128, 0, stream>>>(
        x, Wq, bq, Wkx, bkx, Wvx, bvx, Wout, bout, ln_scale, ln_bias,
        Mw, Ksw, Vsw, (float*)d_out);
}

// Round 2
// 136.048 us; speedup vs baseline: 1.2244x; 1.2244x over previous
//
#include <hip/hip_runtime.h>
#include <hip/hip_bf16.h>

#define BB 4
#define SS 256
#define DD 512
#define CC 128
#define NC 64
#define PXB 8   // pixels per block in pixel kernel

// ---------------------------------------------------------------------------
// Kernel 1: text projections. te = s*a; ks = te@Wks+bks; vs = te@Wvs+bvs
// 256 blocks x 256 threads. 4 rows/block. wave = (matrix m, k-half h).
// ---------------------------------------------------------------------------
__global__ __launch_bounds__(256) void text_proj_kernel(
    const float* __restrict__ s, const float* __restrict__ a,
    const float* __restrict__ Wks, const float* __restrict__ bks,
    const float* __restrict__ Wvs, const float* __restrict__ bvs,
    float* __restrict__ ksw, float* __restrict__ vsw)
{
    __shared__ float tel[4][DD];
    __shared__ float part[2][2][4][NC];
    const int t = threadIdx.x;
    const int w = t >> 6;
    const int lane = t & 63;
    const int row0 = blockIdx.x * 4;

    {
        const float4* s4 = (const float4*)(s + (size_t)row0 * DD);
        for (int i = t; i < 512; i += 256) {
            const int r = i >> 7;
            const float am = a[row0 + r];
            float4 v = s4[i];
            v.x *= am; v.y *= am; v.z *= am; v.w *= am;
            ((float4*)&tel[0][0])[i] = v;
        }
    }
    __syncthreads();

    const int m = w & 1;
    const int h = w >> 1;
    const float* __restrict__ Wm = m ? Wvs : Wks;
    const int kb = h * 256;
    float a0 = 0.f, a1 = 0.f, a2 = 0.f, a3 = 0.f;
    #pragma unroll 4
    for (int k = 0; k < 256; ++k) {
        const float wv = Wm[(size_t)(kb + k) * NC + lane];
        a0 = fmaf(tel[0][kb + k], wv, a0);
        a1 = fmaf(tel[1][kb + k], wv, a1);
        a2 = fmaf(tel[2][kb + k], wv, a2);
        a3 = fmaf(tel[3][kb + k], wv, a3);
    }
    part[m][h][0][lane] = a0; part[m][h][1][lane] = a1;
    part[m][h][2][lane] = a2; part[m][h][3][lane] = a3;
    __syncthreads();

    for (int i = t; i < 512; i += 256) {
        const int mm = i >> 8;
        const int r = (i >> 6) & 3;
        const int col = i & 63;
        const float v = part[mm][0][r][col] + part[mm][1][r][col]
                      + (mm ? bvs[col] : bks[col]);
        float* dst = mm ? vsw : ksw;
        dst[(size_t)(row0 + r) * NC + col] = v;
    }
}

// ---------------------------------------------------------------------------
// Kernel 2: per-batch reductions. M = vs^T ks, Ks = sum_s ks, Vs = sum_s vs.
// 256 blocks (b,c) x 256 threads; wave w covers s in [64w, 64w+64).
// ---------------------------------------------------------------------------
__global__ __launch_bounds__(256) void reduce_kernel(
    const float* __restrict__ ksw, const float* __restrict__ vsw,
    float* __restrict__ Mw, float* __restrict__ Ksw, float* __restrict__ Vsw)
{
    __shared__ float pm[4][NC], pk[4][NC], pv[4];
    const int t = threadIdx.x, w = t >> 6, d = t & 63;
    const int b = blockIdx.x >> 6, c = blockIdx.x & 63;
    const float* __restrict__ vsb = vsw + (size_t)b * SS * NC;
    const float* __restrict__ ksb = ksw + (size_t)b * SS * NC;
    float acc = 0.f, ks_ = 0.f, vs_ = 0.f;
    #pragma unroll 4
    for (int j = 0; j < 64; ++j) {
        const int s2 = w * 64 + j;
        const float vv = vsb[s2 * NC + c];
        const float kv = ksb[s2 * NC + d];
        acc = fmaf(vv, kv, acc);
        ks_ += kv; vs_ += vv;
    }
    pm[w][d] = acc; pk[w][d] = ks_;
    if (d == 0) pv[w] = vs_;
    __syncthreads();
    if (t < 64) {
        Mw[((size_t)b * NC + c) * NC + t] = pm[0][t] + pm[1][t] + pm[2][t] + pm[3][t];
        if (c == 0) Ksw[b * NC + t] = pk[0][t] + pk[1][t] + pk[2][t] + pk[3][t];
        if (t == 0) Vsw[b * NC + c] = pv[0] + pv[1] + pv[2] + pv[3];
    }
}

// ---------------------------------------------------------------------------
// Kernel 3: per-pixel attention + out proj + residual + LN.
// 512 blocks x 512 threads, 8 pixels/block. LDS ~58 KB -> 2 blocks/CU.
// A[c,d] = ((256*vx[c]+Vs[c])*kx[d] + vx[c]*Ks[d] + M[c,d]) / 8
// ---------------------------------------------------------------------------
__global__ __launch_bounds__(512) void pixel_kernel(
    const float* __restrict__ x,
    const float* __restrict__ Wq,  const float* __restrict__ bq,
    const float* __restrict__ Wkx, const float* __restrict__ bkx,
    const float* __restrict__ Wvx, const float* __restrict__ bvx,
    const float* __restrict__ Wout, const float* __restrict__ bout,
    const float* __restrict__ ln_scale, const float* __restrict__ ln_bias,
    const float* __restrict__ Mw, const float* __restrict__ Ksw,
    const float* __restrict__ Vsw,
    float* __restrict__ out)
{
    __shared__ float Wc[32 * 192];
    __shared__ float xl[PXB][CC];
    __shared__ float Ml[NC * 65];
    __shared__ float proj[3][PXB][NC];
    __shared__ float rsl[PXB][NC];
    __shared__ float mxl[PXB][NC];
    __shared__ float outl[PXB][NC];
    __shared__ float Ksl[NC], Vsl[NC];
    __shared__ float redl[4][2][4];

    const int t = threadIdx.x;
    const int w = t >> 6, lane = t & 63;
    const int px0g = blockIdx.x * PXB;
    const int b = px0g >> 10;

    {
        const float4* x4 = (const float4*)(x + (size_t)px0g * CC);
        for (int i = t; i < PXB * CC / 4; i += 512)
            ((float4*)&xl[0][0])[i] = x4[i];
        const float* Mb = Mw + (size_t)b * NC * NC;
        for (int i = t; i < NC * NC; i += 512)
            Ml[(i >> 6) * 65 + (i & 63)] = Mb[i];
        if (t < NC) { Ksl[t] = Ksw[b * NC + t]; Vsl[t] = Vsw[b * NC + t]; }
    }

    float4 pre0, pre1, pre2;
    {
        #pragma unroll
        for (int i = 0; i < 3; ++i) {
            const int flat = (t + i * 512) * 4;
            const int kk2 = flat / 192, col = flat % 192;
            const int seg = col >> 6, c0 = col & 63;
            const float* p = (seg == 0) ? Wq : (seg == 1 ? Wkx : Wvx);
            const float4 v = *(const float4*)(p + (size_t)kk2 * NC + c0);
            if (i == 0) pre0 = v; else if (i == 1) pre1 = v; else pre2 = v;
        }
    }
    const int mm = w % 3;
    const int g  = w / 3;
    float acc0 = 0.f, acc1 = 0.f, acc2 = 0.f, acc3 = 0.f;
    for (int kc = 0; kc < 4; ++kc) {
        ((float4*)Wc)[t]        = pre0;
        ((float4*)Wc)[t + 512]  = pre1;
        ((float4*)Wc)[t + 1024] = pre2;
        __syncthreads();
        if (kc < 3) {
            #pragma unroll
            for (int i = 0; i < 3; ++i) {
                const int flat = (t + i * 512) * 4;
                const int kk2 = flat / 192, col = flat % 192;
                const int seg = col >> 6, c0 = col & 63;
                const float* p = (seg == 0) ? Wq : (seg == 1 ? Wkx : Wvx);
                const float4 v = *(const float4*)(p + (size_t)((kc + 1) * 32 + kk2) * NC + c0);
                if (i == 0) pre0 = v; else if (i == 1) pre1 = v; else pre2 = v;
            }
        }
        if (w < 6) {
            const int kb = kc * 32;
            #pragma unroll
            for (int k4 = 0; k4 < 8; ++k4) {
                const float4 x0 = *(const float4*)&xl[4 * g + 0][kb + k4 * 4];
                const float4 x1 = *(const float4*)&xl[4 * g + 1][kb + k4 * 4];
                const float4 x2 = *(const float4*)&xl[4 * g + 2][kb + k4 * 4];
                const float4 x3 = *(const float4*)&xl[4 * g + 3][kb + k4 * 4];
                #pragma unroll
                for (int q = 0; q < 4; ++q) {
                    const float wv = Wc[(k4 * 4 + q) * 192 + mm * 64 + lane];
                    const float e0 = (q == 0) ? x0.x : (q == 1) ? x0.y : (q == 2) ? x0.z : x0.w;
                    const float e1 = (q == 0) ? x1.x : (q == 1) ? x1.y : (q == 2) ? x1.z : x1.w;
                    const float e2 = (q == 0) ? x2.x : (q == 1) ? x2.y : (q == 2) ? x2.z : x2.w;
                    const float e3 = (q == 0) ? x3.x : (q == 1) ? x3.y : (q == 2) ? x3.z : x3.w;
                    acc0 = fmaf(e0, wv, acc0);
                    acc1 = fmaf(e1, wv, acc1);
                    acc2 = fmaf(e2, wv, acc2);
                    acc3 = fmaf(e3, wv, acc3);
                }
            }
        }
        __syncthreads();
    }
    if (w < 6) {
        const float* bias = (mm == 0) ? bq : (mm == 1 ? bkx : bvx);
        const float bb = bias[lane];
        proj[mm][4 * g + 0][lane] = acc0 + bb;
        proj[mm][4 * g + 1][lane] = acc1 + bb;
        proj[mm][4 * g + 2][lane] = acc2 + bb;
        proj[mm][4 * g + 3][lane] = acc3 + bb;
    }
    __syncthreads();

    {
        const int px = w, c = lane;
        const float vxc = proj[2][px][c];
        const float qc  = proj[0][px][c];
        const float uc  = fmaf(256.0f, vxc, Vsl[c]);
        float row[NC];
        float mx = -3.4e38f;
        #pragma unroll
        for (int d = 0; d < NC; ++d) {
            const float A = fmaf(uc, proj[1][px][d],
                                 fmaf(vxc, Ksl[d], Ml[c * 65 + d])) * 0.125f;
            row[d] = A;
            mx = fmaxf(mx, A);
        }
        float sum = 0.f;
        #pragma unroll
        for (int d = 0; d < NC; ++d) sum += __expf(row[d] - mx);
        rsl[px][c] = qc / sum;
        mxl[px][c] = mx;
    }
    __syncthreads();

    {
        const int px = w, d = lane;
        const float kxd = proj[1][px][d];
        const float Ksd = Ksl[d];
        float acc = 0.f;
        #pragma unroll 4
        for (int c = 0; c < NC; ++c) {
            const float vxc = proj[2][px][c];
            const float uc = fmaf(256.0f, vxc, Vsl[c]);
            const float A = fmaf(uc, kxd, fmaf(vxc, Ksd, Ml[c * 65 + d])) * 0.125f;
            acc = fmaf(rsl[px][c], __expf(A - mxl[px][c]), acc);
        }
        outl[px][d] = acc;
    }
    __syncthreads();

    {
        const int col = t & 127;
        const int pxg = t >> 7;
        const int px0 = 2 * pxg, px1 = px0 + 1;
        float acc0 = 0.f, acc1 = 0.f;
        #pragma unroll 4
        for (int k = 0; k < NC; ++k) {
            const float wv = Wout[k * CC + col];
            acc0 = fmaf(outl[px0][k], wv, acc0);
            acc1 = fmaf(outl[px1][k], wv, acc1);
        }
        const float bb = bout[col];
        const float y0 = acc0 + bb + xl[px0][col];
        const float y1 = acc1 + bb + xl[px1][col];

        float s10 = y0, s20 = y0 * y0, s11 = y1, s21 = y1 * y1;
        #pragma unroll
        for (int off = 32; off >= 1; off >>= 1) {
            s10 += __shfl_down(s10, off);
            s20 += __shfl_down(s20, off);
            s11 += __shfl_down(s11, off);
            s21 += __shfl_down(s21, off);
        }
        const int half = (t >> 6) & 1;
        if (lane == 0) {
            redl[pxg][half][0] = s10; redl[pxg][half][1] = s20;
            redl[pxg][half][2] = s11; redl[pxg][half][3] = s21;
        }
        __syncthreads();
        const float S10 = redl[pxg][0][0] + redl[pxg][1][0];
        const float S20 = redl[pxg][0][1] + redl[pxg][1][1];
        const float S11 = redl[pxg][0][2] + redl[pxg][1][2];
        const float S21 = redl[pxg][0][3] + redl[pxg][1][3];
        const float mu0 = S10 * (1.f / 128.f);
        const float var0 = S20 * (1.f / 128.f) - mu0 * mu0;
        const float mu1 = S11 * (1.f / 128.f);
        const float var1 = S21 * (1.f / 128.f) - mu1 * mu1;
        const float r0 = rsqrtf(var0 + 1e-6f), r1 = rsqrtf(var1 + 1e-6f);
        const float gg = ln_scale[col], be = ln_bias[col];
        out[(size_t)(px0g + px0) * CC + col] = (y0 - mu0) * r0 * gg + be;
        out[(size_t)(px0g + px1) * CC + col] = (y1 - mu1) * r1 * gg + be;
    }
}

// ---------------------------------------------------------------------------
extern "C" void kernel_launch(void* const* d_in, const int* in_sizes, int n_in,
                              void* d_out, int out_size, void* d_ws, size_t ws_size,
                              hipStream_t stream) {
    const float* x        = (const float*)d_in[0];
    const float* s        = (const float*)d_in[1];
    const float* a        = (const float*)d_in[2];
    const float* Wq       = (const float*)d_in[3];
    const float* bq       = (const float*)d_in[4];
    const float* Wkx      = (const float*)d_in[5];
    const float* bkx      = (const float*)d_in[6];
    const float* Wvx      = (const float*)d_in[7];
    const float* bvx      = (const float*)d_in[8];
    const float* Wks      = (const float*)d_in[9];
    const float* bks      = (const float*)d_in[10];
    const float* Wvs      = (const float*)d_in[11];
    const float* bvs      = (const float*)d_in[12];
    const float* Wout     = (const float*)d_in[13];
    const float* bout     = (const float*)d_in[14];
    const float* ln_scale = (const float*)d_in[15];
    const float* ln_bias  = (const float*)d_in[16];

    float* ws  = (float*)d_ws;
    float* ksw = ws;                 // 65536
    float* vsw = ws + 65536;         // 65536
    float* Mw  = ws + 131072;        // 16384
    float* Ksw = ws + 147456;        // 256
    float* Vsw = ws + 147712;        // 256

    text_proj_kernel<<<(BB * SS) / 4, 256, 0, stream>>>(s, a, Wks, bks, Wvs, bvs, ksw, vsw);
    reduce_kernel<<<BB * NC, 256, 0, stream>>>(ksw, vsw, Mw, Ksw, Vsw);
    pixel_kernel<<<(BB * 1024) / PXB, 512, 0, stream>>>(
        x, Wq, bq, Wkx, bkx, Wvx, bvx, Wout, bout, ln_scale, ln_bias,
        Mw, Ksw, Vsw, (float*)d_out);
}

// Round 3
// 127.594 us; speedup vs baseline: 1.3056x; 1.0663x over previous
//
#include <hip/hip_runtime.h>
#include <hip/hip_bf16.h>

#define BB 4
#define SS 256
#define DD 512
#define CC 128
#define NC 64
#define PXB 4    // pixels per block in pixel kernel

// ---------------------------------------------------------------------------
// Kernel 1: x projections. P[px][0:64]=q, [64:128]=kx, [128:192]=vx.
// 512 blocks x 192 thr; 8 pixels/block; wave = matrix; 8-way ILP over pixels.
// ---------------------------------------------------------------------------
__global__ __launch_bounds__(192) void xproj_kernel(
    const float* __restrict__ x,
    const float* __restrict__ Wq,  const float* __restrict__ bq,
    const float* __restrict__ Wkx, const float* __restrict__ bkx,
    const float* __restrict__ Wvx, const float* __restrict__ bvx,
    float* __restrict__ P)
{
    __shared__ float xl[8][CC];     // 4 KB
    const int t = threadIdx.x;
    const int w = t >> 6, lane = t & 63;
    const int px0 = blockIdx.x * 8;

    {
        const float4* x4 = (const float4*)(x + (size_t)px0 * CC);
        for (int i = t; i < 8 * CC / 4; i += 192)
            ((float4*)&xl[0][0])[i] = x4[i];
    }
    __syncthreads();

    const float* __restrict__ Wm = (w == 0) ? Wq : (w == 1 ? Wkx : Wvx);
    const float* __restrict__ bm = (w == 0) ? bq : (w == 1 ? bkx : bvx);
    float a0=0.f,a1=0.f,a2=0.f,a3=0.f,a4=0.f,a5=0.f,a6=0.f,a7=0.f;
    #pragma unroll 4
    for (int k = 0; k < CC; ++k) {
        const float wv = Wm[(size_t)k * NC + lane];
        a0 = fmaf(xl[0][k], wv, a0);
        a1 = fmaf(xl[1][k], wv, a1);
        a2 = fmaf(xl[2][k], wv, a2);
        a3 = fmaf(xl[3][k], wv, a3);
        a4 = fmaf(xl[4][k], wv, a4);
        a5 = fmaf(xl[5][k], wv, a5);
        a6 = fmaf(xl[6][k], wv, a6);
        a7 = fmaf(xl[7][k], wv, a7);
    }
    const float bb = bm[lane];
    float* dst = P + (size_t)px0 * 192 + w * 64 + lane;
    dst[0*192] = a0 + bb; dst[1*192] = a1 + bb;
    dst[2*192] = a2 + bb; dst[3*192] = a3 + bb;
    dst[4*192] = a4 + bb; dst[5*192] = a5 + bb;
    dst[6*192] = a6 + bb; dst[7*192] = a7 + bb;
}

// ---------------------------------------------------------------------------
// Kernel 2: text projections. te = s*a; ks = te@Wks+bks; vs = te@Wvs+bvs
// 512 blocks x 256 thr; 2 rows/block; wave=(matrix m, k-half h).
// float4 weight loads: lane = (ksub = lane>>4, colgroup = lane&15).
// ---------------------------------------------------------------------------
__global__ __launch_bounds__(256) void text_proj_kernel(
    const float* __restrict__ s, const float* __restrict__ a,
    const float* __restrict__ Wks, const float* __restrict__ bks,
    const float* __restrict__ Wvs, const float* __restrict__ bvs,
    float* __restrict__ ksw, float* __restrict__ vsw)
{
    __shared__ float tel[2][DD];          // 4 KB
    __shared__ float part[2][2][2][NC];   // 2 KB  [m][h][r][col]
    const int t = threadIdx.x;
    const int w = t >> 6, lane = t & 63;
    const int row0 = blockIdx.x * 2;

    {
        const float4* s4 = (const float4*)(s + (size_t)row0 * DD);
        const int i = t;                  // 256 float4 = 2*512 floats
        const int r = i >> 7;
        const float am = a[row0 + r];
        float4 v = s4[i];
        v.x *= am; v.y *= am; v.z *= am; v.w *= am;
        ((float4*)&tel[0][0])[i] = v;
    }
    __syncthreads();

    const int m = w & 1, h = w >> 1;
    const int kb = h * 256;
    const int cg = (lane & 15) * 4;       // col group base
    const int ksub = lane >> 4;           // 0..3
    const float* __restrict__ Wm = m ? Wvs : Wks;

    float4 acc0 = {0,0,0,0}, acc1 = {0,0,0,0};
    #pragma unroll 4
    for (int j = 0; j < 64; ++j) {
        const int k = kb + 4 * j + ksub;
        const float4 wv = *(const float4*)(Wm + (size_t)k * NC + cg);
        const float t0 = tel[0][k];
        const float t1 = tel[1][k];
        acc0.x = fmaf(t0, wv.x, acc0.x); acc0.y = fmaf(t0, wv.y, acc0.y);
        acc0.z = fmaf(t0, wv.z, acc0.z); acc0.w = fmaf(t0, wv.w, acc0.w);
        acc1.x = fmaf(t1, wv.x, acc1.x); acc1.y = fmaf(t1, wv.y, acc1.y);
        acc1.z = fmaf(t1, wv.z, acc1.z); acc1.w = fmaf(t1, wv.w, acc1.w);
    }
    // reduce over ksub (lanes l, l+16, l+32, l+48)
    #pragma unroll
    for (int off = 16; off <= 32; off <<= 1) {
        acc0.x += __shfl_down(acc0.x, off); acc0.y += __shfl_down(acc0.y, off);
        acc0.z += __shfl_down(acc0.z, off); acc0.w += __shfl_down(acc0.w, off);
        acc1.x += __shfl_down(acc1.x, off); acc1.y += __shfl_down(acc1.y, off);
        acc1.z += __shfl_down(acc1.z, off); acc1.w += __shfl_down(acc1.w, off);
    }
    if (lane < 16) {
        *(float4*)&part[m][h][0][cg] = acc0;
        *(float4*)&part[m][h][1][cg] = acc1;
    }
    __syncthreads();

    // t covers 2 mats x 2 rows x 64 cols = 256 outputs
    {
        const int mm = t >> 7, r = (t >> 6) & 1, col = t & 63;
        const float v = part[mm][0][r][col] + part[mm][1][r][col]
                      + (mm ? bvs[col] : bks[col]);
        float* dst = mm ? vsw : ksw;
        dst[(size_t)(row0 + r) * NC + col] = v;
    }
}

// ---------------------------------------------------------------------------
// Kernel 3: per-batch reductions. M = vs^T ks, Ks = sum_s ks, Vs = sum_s vs.
// 256 blocks (b,c) x 256 thr; wave w covers s in [64w, 64w+64).
// ---------------------------------------------------------------------------
__global__ __launch_bounds__(256) void reduce_kernel(
    const float* __restrict__ ksw, const float* __restrict__ vsw,
    float* __restrict__ Mw, float* __restrict__ Ksw, float* __restrict__ Vsw)
{
    __shared__ float pm[4][NC], pk[4][NC], pv[4];
    const int t = threadIdx.x, w = t >> 6, d = t & 63;
    const int b = blockIdx.x >> 6, c = blockIdx.x & 63;
    const float* __restrict__ vsb = vsw + (size_t)b * SS * NC;
    const float* __restrict__ ksb = ksw + (size_t)b * SS * NC;
    float acc = 0.f, ks_ = 0.f, vs_ = 0.f;
    #pragma unroll 4
    for (int j = 0; j < 64; ++j) {
        const int s2 = w * 64 + j;
        const float vv = vsb[s2 * NC + c];
        const float kv = ksb[s2 * NC + d];
        acc = fmaf(vv, kv, acc);
        ks_ += kv; vs_ += vv;
    }
    pm[w][d] = acc; pk[w][d] = ks_;
    if (d == 0) pv[w] = vs_;
    __syncthreads();
    if (t < 64) {
        Mw[((size_t)b * NC + c) * NC + t] = pm[0][t] + pm[1][t] + pm[2][t] + pm[3][t];
        if (c == 0) Ksw[b * NC + t] = pk[0][t] + pk[1][t] + pk[2][t] + pk[3][t];
        if (t == 0) Vsw[b * NC + c] = pv[0] + pv[1] + pv[2] + pv[3];
    }
}

// ---------------------------------------------------------------------------
// Kernel 4: per-pixel attention + out proj + residual + LN. Projections come
// precomputed in P. 1024 blocks x 256 thr, 4 pixels/block, LDS ~25 KB.
// A[c,d] = ((256*vx[c]+Vs[c])*kx[d] + vx[c]*Ks[d] + M[c,d]) / 8
// ---------------------------------------------------------------------------
__global__ __launch_bounds__(256) void pixel_kernel(
    const float* __restrict__ x, const float* __restrict__ P,
    const float* __restrict__ Wout, const float* __restrict__ bout,
    const float* __restrict__ ln_scale, const float* __restrict__ ln_bias,
    const float* __restrict__ Mw, const float* __restrict__ Ksw,
    const float* __restrict__ Vsw,
    float* __restrict__ out)
{
    __shared__ float Ml[NC * 65];        // 16.25 KB
    __shared__ float projl[PXB][192];    // 3 KB
    __shared__ float xl[PXB][CC];        // 2 KB
    __shared__ float rsl[PXB][NC];
    __shared__ float mxl[PXB][NC];
    __shared__ float outl[PXB][NC];
    __shared__ float Ksl[NC], Vsl[NC];
    __shared__ float redl[2][2][4];

    const int t = threadIdx.x;
    const int w = t >> 6, lane = t & 63;
    const int px0g = blockIdx.x * PXB;
    const int b = px0g >> 10;

    // ---- stage ----
    {
        const float4* P4 = (const float4*)(P + (size_t)px0g * 192);
        for (int i = t; i < PXB * 192 / 4; i += 256)
            ((float4*)&projl[0][0])[i] = P4[i];
        const float4* x4 = (const float4*)(x + (size_t)px0g * CC);
        for (int i = t; i < PXB * CC / 4; i += 256)
            ((float4*)&xl[0][0])[i] = x4[i];
        const float* Mb = Mw + (size_t)b * NC * NC;
        for (int i = t; i < NC * NC; i += 256)
            Ml[(i >> 6) * 65 + (i & 63)] = Mb[i];
        if (t < NC) { Ksl[t] = Ksw[b * NC + t]; Vsl[t] = Vsw[b * NC + t]; }
    }
    __syncthreads();

    // ---- pass 1: wave = pixel, lane = row c: softmax stats ----
    {
        const int px = w, c = lane;
        const float vxc = projl[px][128 + c];
        const float qc  = projl[px][c];
        const float uc  = fmaf(256.0f, vxc, Vsl[c]);
        float row[NC];
        float mx = -3.4e38f;
        #pragma unroll
        for (int d = 0; d < NC; ++d) {
            const float A = fmaf(uc, projl[px][64 + d],
                                 fmaf(vxc, Ksl[d], Ml[c * 65 + d])) * 0.125f;
            row[d] = A;
            mx = fmaxf(mx, A);
        }
        float sum = 0.f;
        #pragma unroll
        for (int d = 0; d < NC; ++d) sum += __expf(row[d] - mx);
        rsl[px][c] = qc / sum;
        mxl[px][c] = mx;
    }
    __syncthreads();

    // ---- pass 2: wave = pixel, lane = col d: out[d] = sum_c rs[c]*exp(A) ----
    {
        const int px = w, d = lane;
        const float kxd = projl[px][64 + d];
        const float Ksd = Ksl[d];
        float acc = 0.f;
        #pragma unroll 4
        for (int c = 0; c < NC; ++c) {
            const float vxc = projl[px][128 + c];
            const float uc = fmaf(256.0f, vxc, Vsl[c]);
            const float A = fmaf(uc, kxd, fmaf(vxc, Ksd, Ml[c * 65 + d])) * 0.125f;
            acc = fmaf(rsl[px][c], __expf(A - mxl[px][c]), acc);
        }
        outl[px][d] = acc;
    }
    __syncthreads();

    // ---- out proj + residual + layernorm (thread = (pixel-pair, col)) ----
    {
        const int col = t & 127;
        const int pxg = t >> 7;            // 0..1
        const int px0 = 2 * pxg, px1 = px0 + 1;
        float acc0 = 0.f, acc1 = 0.f;
        #pragma unroll 4
        for (int k = 0; k < NC; ++k) {
            const float wv = Wout[k * CC + col];
            acc0 = fmaf(outl[px0][k], wv, acc0);
            acc1 = fmaf(outl[px1][k], wv, acc1);
        }
        const float bb = bout[col];
        const float y0 = acc0 + bb + xl[px0][col];
        const float y1 = acc1 + bb + xl[px1][col];

        float s10 = y0, s20 = y0 * y0, s11 = y1, s21 = y1 * y1;
        #pragma unroll
        for (int off = 32; off >= 1; off >>= 1) {
            s10 += __shfl_down(s10, off);
            s20 += __shfl_down(s20, off);
            s11 += __shfl_down(s11, off);
            s21 += __shfl_down(s21, off);
        }
        const int half = (t >> 6) & 1;
        if (lane == 0) {
            redl[pxg][half][0] = s10; redl[pxg][half][1] = s20;
            redl[pxg][half][2] = s11; redl[pxg][half][3] = s21;
        }
        __syncthreads();
        const float S10 = redl[pxg][0][0] + redl[pxg][1][0];
        const float S20 = redl[pxg][0][1] + redl[pxg][1][1];
        const float S11 = redl[pxg][0][2] + redl[pxg][1][2];
        const float S21 = redl[pxg][0][3] + redl[pxg][1][3];
        const float mu0 = S10 * (1.f / 128.f);
        const float var0 = S20 * (1.f / 128.f) - mu0 * mu0;
        const float mu1 = S11 * (1.f / 128.f);
        const float var1 = S21 * (1.f / 128.f) - mu1 * mu1;
        const float r0 = rsqrtf(var0 + 1e-6f), r1 = rsqrtf(var1 + 1e-6f);
        const float gg = ln_scale[col], be = ln_bias[col];
        out[(size_t)(px0g + px0) * CC + col] = (y0 - mu0) * r0 * gg + be;
        out[(size_t)(px0g + px1) * CC + col] = (y1 - mu1) * r1 * gg + be;
    }
}

// ---------------------------------------------------------------------------
extern "C" void kernel_launch(void* const* d_in, const int* in_sizes, int n_in,
                              void* d_out, int out_size, void* d_ws, size_t ws_size,
                              hipStream_t stream) {
    const float* x        = (const float*)d_in[0];
    const float* s        = (const float*)d_in[1];
    const float* a        = (const float*)d_in[2];
    const float* Wq       = (const float*)d_in[3];
    const float* bq       = (const float*)d_in[4];
    const float* Wkx      = (const float*)d_in[5];
    const float* bkx      = (const float*)d_in[6];
    const float* Wvx      = (const float*)d_in[7];
    const float* bvx      = (const float*)d_in[8];
    const float* Wks      = (const float*)d_in[9];
    const float* bks      = (const float*)d_in[10];
    const float* Wvs      = (const float*)d_in[11];
    const float* bvs      = (const float*)d_in[12];
    const float* Wout     = (const float*)d_in[13];
    const float* bout     = (const float*)d_in[14];
    const float* ln_scale = (const float*)d_in[15];
    const float* ln_bias  = (const float*)d_in[16];

    float* ws  = (float*)d_ws;
    float* ksw = ws;                 // 65536
    float* vsw = ws + 65536;         // 65536
    float* Mw  = ws + 131072;        // 16384
    float* Ksw = ws + 147456;        // 256
    float* Vsw = ws + 147712;        // 256
    float* Pw  = ws + 147968;        // 4096*192 = 786432

    xproj_kernel<<<512, 192, 0, stream>>>(x, Wq, bq, Wkx, bkx, Wvx, bvx, Pw);
    text_proj_kernel<<<(BB * SS) / 2, 256, 0, stream>>>(s, a, Wks, bks, Wvs, bvs, ksw, vsw);
    reduce_kernel<<<BB * NC, 256, 0, stream>>>(ksw, vsw, Mw, Ksw, Vsw);
    pixel_kernel<<<(BB * 1024) / PXB, 256, 0, stream>>>(
        x, Pw, Wout, bout, ln_scale, ln_bias, Mw, Ksw, Vsw, (float*)d_out);
}

// Round 4
// 118.174 us; speedup vs baseline: 1.4096x; 1.0797x over previous
//
#include <hip/hip_runtime.h>
#include <hip/hip_bf16.h>

#define BB 4
#define SS 256
#define DD 512
#define CC 128
#define NC 64
#define PXB 4    // pixels per block in pixel kernel

// ---------------------------------------------------------------------------
// Kernel 1 (fused): blocks 0..511 = x projections (8 px/block),
//                   blocks 512..1023 = text projections (2 rows/block).
// Both roles: 256 threads, float4 weight loads, shuffle-reduce over k-sublanes.
// xproj output P[px][0:64]=q, [64:128]=kx, [128:192]=vx.
// ---------------------------------------------------------------------------
__global__ __launch_bounds__(256) void fused_proj_kernel(
    const float* __restrict__ x,
    const float* __restrict__ Wq,  const float* __restrict__ bq,
    const float* __restrict__ Wkx, const float* __restrict__ bkx,
    const float* __restrict__ Wvx, const float* __restrict__ bvx,
    const float* __restrict__ s, const float* __restrict__ a,
    const float* __restrict__ Wks, const float* __restrict__ bks,
    const float* __restrict__ Wvs, const float* __restrict__ bvs,
    float* __restrict__ P, float* __restrict__ ksw, float* __restrict__ vsw)
{
    __shared__ float tel[2][DD];          // text role
    __shared__ float part[2][2][2][NC];   // text role
    __shared__ float xl[8][CC];           // xproj role

    const int t = threadIdx.x;
    const int w = t >> 6, lane = t & 63;

    if (blockIdx.x < 512) {
        // ---------------- xproj role ----------------
        const int px0 = blockIdx.x * 8;
        {
            const float4* x4 = (const float4*)(x + (size_t)px0 * CC);
            ((float4*)&xl[0][0])[t] = x4[t];    // 256 float4 = 8*128 floats
        }
        __syncthreads();
        if (w < 3) {
            const float* __restrict__ Wm = (w == 0) ? Wq : (w == 1 ? Wkx : Wvx);
            const float* __restrict__ bm = (w == 0) ? bq : (w == 1 ? bkx : bvx);
            const int ksub = lane >> 4;        // 0..3
            const int cg = (lane & 15) * 4;    // col group base
            float4 acc[8] = {};
            #pragma unroll 4
            for (int j = 0; j < 32; ++j) {
                const int k = 4 * j + ksub;
                const float4 wv = *(const float4*)(Wm + (size_t)k * NC + cg);
                #pragma unroll
                for (int px = 0; px < 8; ++px) {
                    const float xv = xl[px][k];
                    acc[px].x = fmaf(xv, wv.x, acc[px].x);
                    acc[px].y = fmaf(xv, wv.y, acc[px].y);
                    acc[px].z = fmaf(xv, wv.z, acc[px].z);
                    acc[px].w = fmaf(xv, wv.w, acc[px].w);
                }
            }
            #pragma unroll
            for (int px = 0; px < 8; ++px) {
                #pragma unroll
                for (int off = 16; off <= 32; off <<= 1) {
                    acc[px].x += __shfl_down(acc[px].x, off);
                    acc[px].y += __shfl_down(acc[px].y, off);
                    acc[px].z += __shfl_down(acc[px].z, off);
                    acc[px].w += __shfl_down(acc[px].w, off);
                }
            }
            if (ksub == 0) {
                const float4 bb = *(const float4*)(bm + cg);
                #pragma unroll
                for (int px = 0; px < 8; ++px) {
                    float4 v;
                    v.x = acc[px].x + bb.x; v.y = acc[px].y + bb.y;
                    v.z = acc[px].z + bb.z; v.w = acc[px].w + bb.w;
                    *(float4*)(P + (size_t)(px0 + px) * 192 + w * 64 + cg) = v;
                }
            }
        }
    } else {
        // ---------------- text role ----------------
        const int row0 = (blockIdx.x - 512) * 2;
        {
            const float4* s4 = (const float4*)(s + (size_t)row0 * DD);
            const int r = t >> 7;
            const float am = a[row0 + r];
            float4 v = s4[t];
            v.x *= am; v.y *= am; v.z *= am; v.w *= am;
            ((float4*)&tel[0][0])[t] = v;
        }
        __syncthreads();

        const int m = w & 1, h = w >> 1;
        const int kb = h * 256;
        const int cg = (lane & 15) * 4;
        const int ksub = lane >> 4;
        const float* __restrict__ Wm = m ? Wvs : Wks;

        float4 acc0 = {0,0,0,0}, acc1 = {0,0,0,0};
        #pragma unroll 4
        for (int j = 0; j < 64; ++j) {
            const int k = kb + 4 * j + ksub;
            const float4 wv = *(const float4*)(Wm + (size_t)k * NC + cg);
            const float t0 = tel[0][k];
            const float t1 = tel[1][k];
            acc0.x = fmaf(t0, wv.x, acc0.x); acc0.y = fmaf(t0, wv.y, acc0.y);
            acc0.z = fmaf(t0, wv.z, acc0.z); acc0.w = fmaf(t0, wv.w, acc0.w);
            acc1.x = fmaf(t1, wv.x, acc1.x); acc1.y = fmaf(t1, wv.y, acc1.y);
            acc1.z = fmaf(t1, wv.z, acc1.z); acc1.w = fmaf(t1, wv.w, acc1.w);
        }
        #pragma unroll
        for (int off = 16; off <= 32; off <<= 1) {
            acc0.x += __shfl_down(acc0.x, off); acc0.y += __shfl_down(acc0.y, off);
            acc0.z += __shfl_down(acc0.z, off); acc0.w += __shfl_down(acc0.w, off);
            acc1.x += __shfl_down(acc1.x, off); acc1.y += __shfl_down(acc1.y, off);
            acc1.z += __shfl_down(acc1.z, off); acc1.w += __shfl_down(acc1.w, off);
        }
        if (lane < 16) {
            *(float4*)&part[m][h][0][cg] = acc0;
            *(float4*)&part[m][h][1][cg] = acc1;
        }
        __syncthreads();

        {
            const int mm = t >> 7, r = (t >> 6) & 1, col = t & 63;
            const float v = part[mm][0][r][col] + part[mm][1][r][col]
                          + (mm ? bvs[col] : bks[col]);
            float* dst = mm ? vsw : ksw;
            dst[(size_t)(row0 + r) * NC + col] = v;
        }
    }
}

// ---------------------------------------------------------------------------
// Kernel 2: per-batch reductions. M = vs^T ks, Ks = sum_s ks, Vs = sum_s vs.
// 256 blocks (b,c) x 256 thr; wave w covers s in [64w, 64w+64).
// ---------------------------------------------------------------------------
__global__ __launch_bounds__(256) void reduce_kernel(
    const float* __restrict__ ksw, const float* __restrict__ vsw,
    float* __restrict__ Mw, float* __restrict__ Ksw, float* __restrict__ Vsw)
{
    __shared__ float pm[4][NC], pk[4][NC], pv[4];
    const int t = threadIdx.x, w = t >> 6, d = t & 63;
    const int b = blockIdx.x >> 6, c = blockIdx.x & 63;
    const float* __restrict__ vsb = vsw + (size_t)b * SS * NC;
    const float* __restrict__ ksb = ksw + (size_t)b * SS * NC;
    float acc = 0.f, ks_ = 0.f, vs_ = 0.f;
    #pragma unroll 4
    for (int j = 0; j < 64; ++j) {
        const int s2 = w * 64 + j;
        const float vv = vsb[s2 * NC + c];
        const float kv = ksb[s2 * NC + d];
        acc = fmaf(vv, kv, acc);
        ks_ += kv; vs_ += vv;
    }
    pm[w][d] = acc; pk[w][d] = ks_;
    if (d == 0) pv[w] = vs_;
    __syncthreads();
    if (t < 64) {
        Mw[((size_t)b * NC + c) * NC + t] = pm[0][t] + pm[1][t] + pm[2][t] + pm[3][t];
        if (c == 0) Ksw[b * NC + t] = pk[0][t] + pk[1][t] + pk[2][t] + pk[3][t];
        if (t == 0) Vsw[b * NC + c] = pv[0] + pv[1] + pv[2] + pv[3];
    }
}

// ---------------------------------------------------------------------------
// Kernel 3: per-pixel attention + out proj + residual + LN. Projections come
// precomputed in P. 1024 blocks x 256 thr, 4 pixels/block.
// A[c,d] = ((256*vx[c]+Vs[c])*kx[d] + vx[c]*Ks[d] + M[c,d]) / 8
// ---------------------------------------------------------------------------
__global__ __launch_bounds__(256) void pixel_kernel(
    const float* __restrict__ x, const float* __restrict__ P,
    const float* __restrict__ Wout, const float* __restrict__ bout,
    const float* __restrict__ ln_scale, const float* __restrict__ ln_bias,
    const float* __restrict__ Mw, const float* __restrict__ Ksw,
    const float* __restrict__ Vsw,
    float* __restrict__ out)
{
    __shared__ float Ml[NC * 65];
    __shared__ float projl[PXB][192];
    __shared__ float xl[PXB][CC];
    __shared__ float rsl[PXB][NC];
    __shared__ float mxl[PXB][NC];
    __shared__ float outl[PXB][NC];
    __shared__ float Ksl[NC], Vsl[NC];
    __shared__ float redl[2][2][4];

    const int t = threadIdx.x;
    const int w = t >> 6, lane = t & 63;
    const int px0g = blockIdx.x * PXB;
    const int b = px0g >> 10;

    {
        const float4* P4 = (const float4*)(P + (size_t)px0g * 192);
        for (int i = t; i < PXB * 192 / 4; i += 256)
            ((float4*)&projl[0][0])[i] = P4[i];
        const float4* x4 = (const float4*)(x + (size_t)px0g * CC);
        for (int i = t; i < PXB * CC / 4; i += 256)
            ((float4*)&xl[0][0])[i] = x4[i];
        const float* Mb = Mw + (size_t)b * NC * NC;
        for (int i = t; i < NC * NC; i += 256)
            Ml[(i >> 6) * 65 + (i & 63)] = Mb[i];
        if (t < NC) { Ksl[t] = Ksw[b * NC + t]; Vsl[t] = Vsw[b * NC + t]; }
    }
    __syncthreads();

    // ---- pass 1: wave = pixel, lane = row c: softmax stats (A recomputed) ----
    {
        const int px = w, c = lane;
        const float vxc = projl[px][128 + c];
        const float qc  = projl[px][c];
        const float uc  = fmaf(256.0f, vxc, Vsl[c]);
        float mx = -3.4e38f;
        #pragma unroll
        for (int d = 0; d < NC; ++d) {
            const float A = fmaf(uc, projl[px][64 + d],
                                 fmaf(vxc, Ksl[d], Ml[c * 65 + d])) * 0.125f;
            mx = fmaxf(mx, A);
        }
        float sum = 0.f;
        #pragma unroll
        for (int d = 0; d < NC; ++d) {
            const float A = fmaf(uc, projl[px][64 + d],
                                 fmaf(vxc, Ksl[d], Ml[c * 65 + d])) * 0.125f;
            sum += __expf(A - mx);
        }
        rsl[px][c] = qc / sum;
        mxl[px][c] = mx;
    }
    __syncthreads();

    // ---- pass 2: wave = pixel, lane = col d ----
    {
        const int px = w, d = lane;
        const float kxd = projl[px][64 + d];
        const float Ksd = Ksl[d];
        float acc = 0.f;
        #pragma unroll 4
        for (int c = 0; c < NC; ++c) {
            const float vxc = projl[px][128 + c];
            const float uc = fmaf(256.0f, vxc, Vsl[c]);
            const float A = fmaf(uc, kxd, fmaf(vxc, Ksd, Ml[c * 65 + d])) * 0.125f;
            acc = fmaf(rsl[px][c], __expf(A - mxl[px][c]), acc);
        }
        outl[px][d] = acc;
    }
    __syncthreads();

    // ---- out proj + residual + layernorm ----
    {
        const int col = t & 127;
        const int pxg = t >> 7;
        const int px0 = 2 * pxg, px1 = px0 + 1;
        float acc0 = 0.f, acc1 = 0.f;
        #pragma unroll 4
        for (int k = 0; k < NC; ++k) {
            const float wv = Wout[k * CC + col];
            acc0 = fmaf(outl[px0][k], wv, acc0);
            acc1 = fmaf(outl[px1][k], wv, acc1);
        }
        const float bb = bout[col];
        const float y0 = acc0 + bb + xl[px0][col];
        const float y1 = acc1 + bb + xl[px1][col];

        float s10 = y0, s20 = y0 * y0, s11 = y1, s21 = y1 * y1;
        #pragma unroll
        for (int off = 32; off >= 1; off >>= 1) {
            s10 += __shfl_down(s10, off);
            s20 += __shfl_down(s20, off);
            s11 += __shfl_down(s11, off);
            s21 += __shfl_down(s21, off);
        }
        const int half = (t >> 6) & 1;
        if (lane == 0) {
            redl[pxg][half][0] = s10; redl[pxg][half][1] = s20;
            redl[pxg][half][2] = s11; redl[pxg][half][3] = s21;
        }
        __syncthreads();
        const float S10 = redl[pxg][0][0] + redl[pxg][1][0];
        const float S20 = redl[pxg][0][1] + redl[pxg][1][1];
        const float S11 = redl[pxg][0][2] + redl[pxg][1][2];
        const float S21 = redl[pxg][0][3] + redl[pxg][1][3];
        const float mu0 = S10 * (1.f / 128.f);
        const float var0 = S20 * (1.f / 128.f) - mu0 * mu0;
        const float mu1 = S11 * (1.f / 128.f);
        const float var1 = S21 * (1.f / 128.f) - mu1 * mu1;
        const float r0 = rsqrtf(var0 + 1e-6f), r1 = rsqrtf(var1 + 1e-6f);
        const float gg = ln_scale[col], be = ln_bias[col];
        out[(size_t)(px0g + px0) * CC + col] = (y0 - mu0) * r0 * gg + be;
        out[(size_t)(px0g + px1) * CC + col] = (y1 - mu1) * r1 * gg + be;
    }
}

// ---------------------------------------------------------------------------
extern "C" void kernel_launch(void* const* d_in, const int* in_sizes, int n_in,
                              void* d_out, int out_size, void* d_ws, size_t ws_size,
                              hipStream_t stream) {
    const float* x        = (const float*)d_in[0];
    const float* s        = (const float*)d_in[1];
    const float* a        = (const float*)d_in[2];
    const float* Wq       = (const float*)d_in[3];
    const float* bq       = (const float*)d_in[4];
    const float* Wkx      = (const float*)d_in[5];
    const float* bkx      = (const float*)d_in[6];
    const float* Wvx      = (const float*)d_in[7];
    const float* bvx      = (const float*)d_in[8];
    const float* Wks      = (const float*)d_in[9];
    const float* bks      = (const float*)d_in[10];
    const float* Wvs      = (const float*)d_in[11];
    const float* bvs      = (const float*)d_in[12];
    const float* Wout     = (const float*)d_in[13];
    const float* bout     = (const float*)d_in[14];
    const float* ln_scale = (const float*)d_in[15];
    const float* ln_bias  = (const float*)d_in[16];

    float* ws  = (float*)d_ws;
    float* ksw = ws;                 // 65536
    float* vsw = ws + 65536;         // 65536
    float* Mw  = ws + 131072;        // 16384
    float* Ksw = ws + 147456;        // 256
    float* Vsw = ws + 147712;        // 256
    float* Pw  = ws + 147968;        // 4096*192 = 786432

    fused_proj_kernel<<<1024, 256, 0, stream>>>(
        x, Wq, bq, Wkx, bkx, Wvx, bvx, s, a, Wks, bks, Wvs, bvs, Pw, ksw, vsw);
    reduce_kernel<<<BB * NC, 256, 0, stream>>>(ksw, vsw, Mw, Ksw, Vsw);
    pixel_kernel<<<(BB * 1024) / PXB, 256, 0, stream>>>(
        x, Pw, Wout, bout, ln_scale, ln_bias, Mw, Ksw, Vsw, (float*)d_out);
}